// Round 1
// baseline (4737.365 us; speedup 1.0000x reference)
//
#include <hip/hip_runtime.h>
#include <hip/hip_bf16.h>

// ---------------- constants (fixed problem shape) ----------------
#define DMODEL 1024
#define DINNER 2048
#define DSTATE 16
#define DTRANK 64
#define NLAYER 4
#define SEQ    2048
#define NB     2
#define BL     (NB*SEQ)   // 4096 token rows

typedef __bf16 bf16x8 __attribute__((ext_vector_type(8)));
typedef float  f32x4  __attribute__((ext_vector_type(4)));
typedef unsigned short u16x8 __attribute__((ext_vector_type(8)));

__device__ __forceinline__ unsigned short f2bf(float f) {
  unsigned int x = __builtin_bit_cast(unsigned int, f);
  x += 0x7fffu + ((x >> 16) & 1u);   // round-to-nearest-even
  return (unsigned short)(x >> 16);
}
__device__ __forceinline__ float softplusf(float x) {
  return (x > 20.f) ? x : log1pf(__expf(x));
}
__device__ __forceinline__ float siluf(float x) {
  return x * (1.f / (1.f + __expf(-x)));
}

__device__ __forceinline__ void pack16(const float* p, u16x8& u0, u16x8& u1) {
  float4 f0 = *(const float4*)(p);
  float4 f1 = *(const float4*)(p + 4);
  float4 f2 = *(const float4*)(p + 8);
  float4 f3 = *(const float4*)(p + 12);
  u0[0]=f2bf(f0.x); u0[1]=f2bf(f0.y); u0[2]=f2bf(f0.z); u0[3]=f2bf(f0.w);
  u0[4]=f2bf(f1.x); u0[5]=f2bf(f1.y); u0[6]=f2bf(f1.z); u0[7]=f2bf(f1.w);
  u1[0]=f2bf(f2.x); u1[1]=f2bf(f2.y); u1[2]=f2bf(f2.z); u1[3]=f2bf(f2.w);
  u1[4]=f2bf(f3.x); u1[5]=f2bf(f3.y); u1[6]=f2bf(f3.z); u1[7]=f2bf(f3.w);
}

// ---------------- generic GEMM: C[M,N] = act(A[M,K] * B[N,K]^T + bias) ----------------
// M always multiple of 128 (M=4096). N arbitrary (guarded). K multiple of 32.
// ACT: 0 = none (optional bias add), 1 = softplus(x + bias)
template<int ACT>
__global__ __launch_bounds__(256) void gemm_bt(
    const float* __restrict__ A, int lda,
    const float* __restrict__ B, int ldb,
    float* __restrict__ C, int ldc,
    int N, int K, const float* __restrict__ bias)
{
  __shared__ alignas(16) unsigned short As[128 * 32];
  __shared__ alignas(16) unsigned short Bs[128 * 32];

  const int tid  = threadIdx.x;
  const int bm   = blockIdx.x, bn = blockIdx.y;
  const int wave = tid >> 6,  lane = tid & 63;
  const int wm   = wave >> 1, wn   = wave & 1;
  const int fr   = lane & 15, fq   = lane >> 4;

  // staging: 2 threads per row, 16 f32 -> 16 bf16 each
  const int r  = tid >> 1, hh = tid & 1;
  const int sw = (r & 7) << 4;
  const int offS0 = ((r * 64 + hh * 32)     ) ^ sw;
  const int offS1 = ((r * 64 + hh * 32 + 16)) ^ sw;

  const int rowA = bm * 128 + r;
  const int rowB = bn * 128 + r;
  const float* aRow = A + (size_t)rowA * lda + hh * 16;
  const float* bRow = B + (size_t)rowB * ldb + hh * 16;
  const bool bValid = (rowB < N);

  f32x4 acc[4][4] = {};

  for (int k0 = 0; k0 < K; k0 += 32) {
    {
      u16x8 u0, u1;
      pack16(aRow + k0, u0, u1);
      *(u16x8*)((char*)As + offS0) = u0;
      *(u16x8*)((char*)As + offS1) = u1;
    }
    {
      u16x8 u0 = {}, u1 = {};
      if (bValid) pack16(bRow + k0, u0, u1);
      *(u16x8*)((char*)Bs + offS0) = u0;
      *(u16x8*)((char*)Bs + offS1) = u1;
    }
    __syncthreads();

    bf16x8 af[4], bfr[4];
#pragma unroll
    for (int mi = 0; mi < 4; ++mi) {
      int ra = wm * 64 + mi * 16 + fr;
      af[mi] = *(const bf16x8*)((const char*)As + ((ra * 64 + fq * 16) ^ ((ra & 7) << 4)));
    }
#pragma unroll
    for (int nj = 0; nj < 4; ++nj) {
      int rb = wn * 64 + nj * 16 + fr;
      bfr[nj] = *(const bf16x8*)((const char*)Bs + ((rb * 64 + fq * 16) ^ ((rb & 7) << 4)));
    }
#pragma unroll
    for (int mi = 0; mi < 4; ++mi)
#pragma unroll
      for (int nj = 0; nj < 4; ++nj)
        acc[mi][nj] = __builtin_amdgcn_mfma_f32_16x16x32_bf16(af[mi], bfr[nj], acc[mi][nj], 0, 0, 0);
    __syncthreads();
  }

#pragma unroll
  for (int mi = 0; mi < 4; ++mi)
#pragma unroll
    for (int nj = 0; nj < 4; ++nj)
#pragma unroll
      for (int q = 0; q < 4; ++q) {
        int row = bm * 128 + wm * 64 + mi * 16 + fq * 4 + q;
        int col = bn * 128 + wn * 64 + nj * 16 + fr;
        if (col < N) {
          float v = acc[mi][nj][q];
          if (bias) v += bias[col];
          if (ACT == 1) v = softplusf(v);
          C[(size_t)row * ldc + col] = v;
        }
      }
}

// ---------------- depthwise causal conv (K=4) + SiLU ----------------
// reads xz[:, 0:2048] (stride 4096), writes xpc [BL, 2048]
__global__ __launch_bounds__(256) void conv_silu_kernel(
    const float* __restrict__ xz, const float* __restrict__ cw,
    const float* __restrict__ cb, float* __restrict__ xpc)
{
  int idx = blockIdx.x * 256 + threadIdx.x;   // BL * 512
  int dq  = idx & 511;
  int row = idx >> 9;
  int l   = row & (SEQ - 1);
  int d   = dq << 2;

  float4 bv = *(const float4*)(cb + d);
  float4 w0 = *(const float4*)(cw + (size_t)(d + 0) * 4);
  float4 w1 = *(const float4*)(cw + (size_t)(d + 1) * 4);
  float4 w2 = *(const float4*)(cw + (size_t)(d + 2) * 4);
  float4 w3 = *(const float4*)(cw + (size_t)(d + 3) * 4);

  float a0 = bv.x, a1 = bv.y, a2 = bv.z, a3 = bv.w;
#pragma unroll
  for (int k = 0; k < 4; ++k) {
    int ls = l - 3 + k;
    if (ls >= 0) {
      float4 xv = *(const float4*)(xz + (size_t)(row - 3 + k) * (2 * DINNER) + d);
      float c0 = (k == 0) ? w0.x : (k == 1) ? w0.y : (k == 2) ? w0.z : w0.w;
      float c1 = (k == 0) ? w1.x : (k == 1) ? w1.y : (k == 2) ? w1.z : w1.w;
      float c2 = (k == 0) ? w2.x : (k == 1) ? w2.y : (k == 2) ? w2.z : w2.w;
      float c3 = (k == 0) ? w3.x : (k == 1) ? w3.y : (k == 2) ? w3.z : w3.w;
      a0 += xv.x * c0; a1 += xv.y * c1; a2 += xv.z * c2; a3 += xv.w * c3;
    }
  }
  float4 o;
  o.x = siluf(a0); o.y = siluf(a1); o.z = siluf(a2); o.w = siluf(a3);
  *(float4*)(xpc + (size_t)row * DINNER + d) = o;
}

// ---------------- selective scan ----------------
// one 16-lane group per (b,d); lane n = state index. y overwrites delta buffer.
__global__ __launch_bounds__(256) void scan_kernel(
    float* dy,                         // delta in, y out (aliased)
    const float* __restrict__ u_,      // xpc [BL, DINNER]
    const float* __restrict__ xd,      // xdbl [BL, 96]
    const float* __restrict__ xzb,     // xz [BL, 4096] (z half)
    const float* __restrict__ Alog,    // [DINNER, 16] layer slice
    const float* __restrict__ Dv)      // [DINNER]
{
  int t = blockIdx.x * 256 + threadIdx.x;     // 65536 total
  int n = t & 15;
  int g = t >> 4;
  int d = g & (DINNER - 1);
  int b = g >> 11;

  float An = -__expf(Alog[d * DSTATE + n]);
  float Dd = Dv[d];
  size_t rb = (size_t)b * SEQ;

  float h = 0.f;
  // prefetch l = 0
  float dl = dy [(rb) * DINNER + d];
  float uu = u_ [(rb) * DINNER + d];
  float Bn = xd [(rb) * 96 + 64 + n];
  float Cn = xd [(rb) * 96 + 80 + n];
  float zz = xzb[(rb) * (2 * DINNER) + DINNER + d];

#define SCAN_STEP(L)                                                      \
  {                                                                       \
    float dA = __expf(dl * An);                                           \
    h = dA * h + (dl * uu) * Bn;                                          \
    float yp = h * Cn;                                                    \
    yp += __shfl_xor(yp, 1);                                              \
    yp += __shfl_xor(yp, 2);                                              \
    yp += __shfl_xor(yp, 4);                                              \
    yp += __shfl_xor(yp, 8);                                              \
    if (n == 0) {                                                         \
      dy[(rb + (L)) * DINNER + d] = (yp + uu * Dd) * siluf(zz);           \
    }                                                                     \
  }

  for (int l = 0; l < SEQ - 1; ++l) {
    size_t rr = rb + l + 1;
    float dln = dy [rr * DINNER + d];
    float uun = u_ [rr * DINNER + d];
    float Bnn = xd [rr * 96 + 64 + n];
    float Cnn = xd [rr * 96 + 80 + n];
    float zzn = xzb[rr * (2 * DINNER) + DINNER + d];
    SCAN_STEP(l);
    dl = dln; uu = uun; Bn = Bnn; Cn = Cnn; zz = zzn;
  }
  SCAN_STEP(SEQ - 1);
#undef SCAN_STEP
}

// ---------------- RMSNorm (row = 1024) ----------------
// ADDRES=1: out = res + norm(x)*w  (residual update); ADDRES=0: out = norm(x)*w
template<int ADDRES>
__global__ __launch_bounds__(256) void rmsnorm_kernel(
    const float* __restrict__ x, const float* __restrict__ w,
    const float* __restrict__ res, float* __restrict__ out)
{
  int row = blockIdx.x, tid = threadIdx.x;
  float4 v = *(const float4*)(x + (size_t)row * DMODEL + tid * 4);
  float ss = v.x * v.x + v.y * v.y + v.z * v.z + v.w * v.w;
#pragma unroll
  for (int off = 32; off > 0; off >>= 1) ss += __shfl_xor(ss, off);
  __shared__ float sb[4];
  if ((tid & 63) == 0) sb[tid >> 6] = ss;
  __syncthreads();
  ss = (sb[0] + sb[1]) + (sb[2] + sb[3]);
  float sc = rsqrtf(ss * (1.f / DMODEL) + 1e-5f);
  float4 wv = *(const float4*)(w + tid * 4);
  float4 o;
  o.x = v.x * sc * wv.x; o.y = v.y * sc * wv.y;
  o.z = v.z * sc * wv.z; o.w = v.w * sc * wv.w;
  if (ADDRES) {
    float4 rv = *(const float4*)(res + (size_t)row * DMODEL + tid * 4);
    o.x += rv.x; o.y += rv.y; o.z += rv.z; o.w += rv.w;
  }
  *(float4*)(out + (size_t)row * DMODEL + tid * 4) = o;
}

// ---------------- launcher ----------------
extern "C" void kernel_launch(void* const* d_in, const int* in_sizes, int n_in,
                              void* d_out, int out_size, void* d_ws, size_t ws_size,
                              hipStream_t stream) {
  const float* x        = (const float*)d_in[0];
  const float* emb_w    = (const float*)d_in[1];
  const float* emb_b    = (const float*)d_in[2];
  const float* in_projw = (const float*)d_in[3];
  const float* conv_w   = (const float*)d_in[4];
  const float* conv_b   = (const float*)d_in[5];
  const float* x_projw  = (const float*)d_in[6];
  const float* dt_projw = (const float*)d_in[7];
  const float* dt_projb = (const float*)d_in[8];
  const float* A_log    = (const float*)d_in[9];
  const float* Dvec     = (const float*)d_in[10];
  const float* out_projw= (const float*)d_in[11];
  const float* norm_w   = (const float*)d_in[12];
  const float* head_w   = (const float*)d_in[13];

  float* ws = (float*)d_ws;
  float* h    = ws;                                  //  4M floats [BL,1024]
  float* xz   = h    + (size_t)BL * DMODEL;          // 16M floats [BL,4096]
  float* xpc  = xz   + (size_t)BL * 2 * DINNER;      //  8M floats [BL,2048]
  float* dlt  = xpc  + (size_t)BL * DINNER;          //  8M floats [BL,2048] (delta -> y)
  float* xdbl = dlt  + (size_t)BL * DINNER;          //  [BL,96]
  float* tmp  = xz;                                  // alias: out_proj result [BL,1024]
  float* hn   = xz + (size_t)BL * DMODEL;            // alias: final norm [BL,1024]

  dim3 blk(256);

  // h = x @ emb_w^T + emb_b
  gemm_bt<0><<<dim3(BL / 128, DMODEL / 128), blk, 0, stream>>>(
      x, DMODEL, emb_w, DMODEL, h, DMODEL, DMODEL, DMODEL, emb_b);

  for (int i = 0; i < NLAYER; ++i) {
    const float* in_w = in_projw + (size_t)i * 2 * DINNER * DMODEL;
    const float* cw   = conv_w   + (size_t)i * DINNER * 4;
    const float* cb   = conv_b   + (size_t)i * DINNER;
    const float* xpw  = x_projw  + (size_t)i * (DTRANK + 2 * DSTATE) * DINNER;
    const float* dtw  = dt_projw + (size_t)i * DINNER * DTRANK;
    const float* dtb  = dt_projb + (size_t)i * DINNER;
    const float* Al   = A_log    + (size_t)i * DINNER * DSTATE;
    const float* Dl   = Dvec     + (size_t)i * DINNER;
    const float* ow   = out_projw+ (size_t)i * DMODEL * DINNER;

    // xz = h @ in_w^T   [BL, 4096]
    gemm_bt<0><<<dim3(BL / 128, (2 * DINNER) / 128), blk, 0, stream>>>(
        h, DMODEL, in_w, DMODEL, xz, 2 * DINNER, 2 * DINNER, DMODEL, nullptr);
    // xpc = silu(causal_conv(xz[:, :2048]))
    conv_silu_kernel<<<dim3(BL * (DINNER / 4) / 256), blk, 0, stream>>>(xz, cw, cb, xpc);
    // xdbl = xpc @ xpw^T  [BL, 96]
    gemm_bt<0><<<dim3(BL / 128, 1), blk, 0, stream>>>(
        xpc, DINNER, xpw, DINNER, xdbl, 96, 96, DINNER, nullptr);
    // delta = softplus(xdbl[:, :64] @ dtw^T + dtb)  [BL, 2048]
    gemm_bt<1><<<dim3(BL / 128, DINNER / 128), blk, 0, stream>>>(
        xdbl, 96, dtw, DTRANK, dlt, DINNER, DINNER, DTRANK, dtb);
    // selective scan: y (over dlt)
    scan_kernel<<<dim3(NB * DINNER * DSTATE / 256), blk, 0, stream>>>(
        dlt, xpc, xdbl, xz, Al, Dl);
    // tmp = y @ ow^T  [BL, 1024]
    gemm_bt<0><<<dim3(BL / 128, DMODEL / 128), blk, 0, stream>>>(
        dlt, DINNER, ow, DINNER, tmp, DMODEL, DMODEL, DINNER, nullptr);
    // h = h + rmsnorm(tmp) * norm_w
    rmsnorm_kernel<1><<<dim3(BL), blk, 0, stream>>>(tmp, norm_w, h, h);
  }

  // final norm + head
  rmsnorm_kernel<0><<<dim3(BL), blk, 0, stream>>>(h, norm_w, nullptr, hn);
  gemm_bt<0><<<dim3(BL / 128, DMODEL / 128), blk, 0, stream>>>(
      hn, DMODEL, head_w, DMODEL, (float*)d_out, DMODEL, DMODEL, DMODEL, nullptr);
}

// Round 2
// 3589.131 us; speedup vs baseline: 1.3199x; 1.3199x over previous
//
#include <hip/hip_runtime.h>
#include <hip/hip_bf16.h>

// ---------------- constants (fixed problem shape) ----------------
#define DMODEL 1024
#define DINNER 2048
#define DSTATE 16
#define DTRANK 64
#define NLAYER 4
#define SEQ    2048
#define NB     2
#define BL     (NB*SEQ)   // 4096 token rows

// chunked scan
#define NCH   16
#define CLEN  (SEQ / NCH)   // 128

typedef __bf16 bf16x8 __attribute__((ext_vector_type(8)));
typedef float  f32x4  __attribute__((ext_vector_type(4)));
typedef unsigned short u16x8 __attribute__((ext_vector_type(8)));

__device__ __forceinline__ unsigned short f2bf(float f) {
  unsigned int x = __builtin_bit_cast(unsigned int, f);
  x += 0x7fffu + ((x >> 16) & 1u);   // round-to-nearest-even
  return (unsigned short)(x >> 16);
}
__device__ __forceinline__ float softplusf(float x) {
  return (x > 20.f) ? x : log1pf(__expf(x));
}
__device__ __forceinline__ float siluf(float x) {
  return x * (1.f / (1.f + __expf(-x)));
}

__device__ __forceinline__ void pack16(const float* p, u16x8& u0, u16x8& u1) {
  float4 f0 = *(const float4*)(p);
  float4 f1 = *(const float4*)(p + 4);
  float4 f2 = *(const float4*)(p + 8);
  float4 f3 = *(const float4*)(p + 12);
  u0[0]=f2bf(f0.x); u0[1]=f2bf(f0.y); u0[2]=f2bf(f0.z); u0[3]=f2bf(f0.w);
  u0[4]=f2bf(f1.x); u0[5]=f2bf(f1.y); u0[6]=f2bf(f1.z); u0[7]=f2bf(f1.w);
  u1[0]=f2bf(f2.x); u1[1]=f2bf(f2.y); u1[2]=f2bf(f2.z); u1[3]=f2bf(f2.w);
  u1[4]=f2bf(f3.x); u1[5]=f2bf(f3.y); u1[6]=f2bf(f3.z); u1[7]=f2bf(f3.w);
}

// ---------------- generic GEMM: C[M,N] = act(A[M,K] * B[N,K]^T + bias) ----------------
// M always multiple of 128 (M=4096). N arbitrary (guarded). K multiple of 32.
// ACT: 0 = none (optional bias add), 1 = softplus(x + bias)
template<int ACT>
__global__ __launch_bounds__(256) void gemm_bt(
    const float* __restrict__ A, int lda,
    const float* __restrict__ B, int ldb,
    float* __restrict__ C, int ldc,
    int N, int K, const float* __restrict__ bias)
{
  __shared__ alignas(16) unsigned short As[128 * 32];
  __shared__ alignas(16) unsigned short Bs[128 * 32];

  const int tid  = threadIdx.x;
  const int bm   = blockIdx.x, bn = blockIdx.y;
  const int wave = tid >> 6,  lane = tid & 63;
  const int wm   = wave >> 1, wn   = wave & 1;
  const int fr   = lane & 15, fq   = lane >> 4;

  // staging: 2 threads per row, 16 f32 -> 16 bf16 each
  const int r  = tid >> 1, hh = tid & 1;
  const int sw = (r & 7) << 4;
  const int offS0 = ((r * 64 + hh * 32)     ) ^ sw;
  const int offS1 = ((r * 64 + hh * 32 + 16)) ^ sw;

  const int rowA = bm * 128 + r;
  const int rowB = bn * 128 + r;
  const float* aRow = A + (size_t)rowA * lda + hh * 16;
  const float* bRow = B + (size_t)rowB * ldb + hh * 16;
  const bool bValid = (rowB < N);

  f32x4 acc[4][4] = {};

  for (int k0 = 0; k0 < K; k0 += 32) {
    {
      u16x8 u0, u1;
      pack16(aRow + k0, u0, u1);
      *(u16x8*)((char*)As + offS0) = u0;
      *(u16x8*)((char*)As + offS1) = u1;
    }
    {
      u16x8 u0 = {}, u1 = {};
      if (bValid) pack16(bRow + k0, u0, u1);
      *(u16x8*)((char*)Bs + offS0) = u0;
      *(u16x8*)((char*)Bs + offS1) = u1;
    }
    __syncthreads();

    bf16x8 af[4], bfr[4];
#pragma unroll
    for (int mi = 0; mi < 4; ++mi) {
      int ra = wm * 64 + mi * 16 + fr;
      af[mi] = *(const bf16x8*)((const char*)As + ((ra * 64 + fq * 16) ^ ((ra & 7) << 4)));
    }
#pragma unroll
    for (int nj = 0; nj < 4; ++nj) {
      int rb = wn * 64 + nj * 16 + fr;
      bfr[nj] = *(const bf16x8*)((const char*)Bs + ((rb * 64 + fq * 16) ^ ((rb & 7) << 4)));
    }
#pragma unroll
    for (int mi = 0; mi < 4; ++mi)
#pragma unroll
      for (int nj = 0; nj < 4; ++nj)
        acc[mi][nj] = __builtin_amdgcn_mfma_f32_16x16x32_bf16(af[mi], bfr[nj], acc[mi][nj], 0, 0, 0);
    __syncthreads();
  }

#pragma unroll
  for (int mi = 0; mi < 4; ++mi)
#pragma unroll
    for (int nj = 0; nj < 4; ++nj)
#pragma unroll
      for (int q = 0; q < 4; ++q) {
        int row = bm * 128 + wm * 64 + mi * 16 + fq * 4 + q;
        int col = bn * 128 + wn * 64 + nj * 16 + fr;
        if (col < N) {
          float v = acc[mi][nj][q];
          if (bias) v += bias[col];
          if (ACT == 1) v = softplusf(v);
          C[(size_t)row * ldc + col] = v;
        }
      }
}

// ---------------- depthwise causal conv (K=4) + SiLU ----------------
__global__ __launch_bounds__(256) void conv_silu_kernel(
    const float* __restrict__ xz, const float* __restrict__ cw,
    const float* __restrict__ cb, float* __restrict__ xpc)
{
  int idx = blockIdx.x * 256 + threadIdx.x;   // BL * 512
  int dq  = idx & 511;
  int row = idx >> 9;
  int l   = row & (SEQ - 1);
  int d   = dq << 2;

  float4 bv = *(const float4*)(cb + d);
  float4 w0 = *(const float4*)(cw + (size_t)(d + 0) * 4);
  float4 w1 = *(const float4*)(cw + (size_t)(d + 1) * 4);
  float4 w2 = *(const float4*)(cw + (size_t)(d + 2) * 4);
  float4 w3 = *(const float4*)(cw + (size_t)(d + 3) * 4);

  float a0 = bv.x, a1 = bv.y, a2 = bv.z, a3 = bv.w;
#pragma unroll
  for (int k = 0; k < 4; ++k) {
    int ls = l - 3 + k;
    if (ls >= 0) {
      float4 xv = *(const float4*)(xz + (size_t)(row - 3 + k) * (2 * DINNER) + d);
      float c0 = (k == 0) ? w0.x : (k == 1) ? w0.y : (k == 2) ? w0.z : w0.w;
      float c1 = (k == 0) ? w1.x : (k == 1) ? w1.y : (k == 2) ? w1.z : w1.w;
      float c2 = (k == 0) ? w2.x : (k == 1) ? w2.y : (k == 2) ? w2.z : w2.w;
      float c3 = (k == 0) ? w3.x : (k == 1) ? w3.y : (k == 2) ? w3.z : w3.w;
      a0 += xv.x * c0; a1 += xv.y * c1; a2 += xv.z * c2; a3 += xv.w * c3;
    }
  }
  float4 o;
  o.x = siluf(a0); o.y = siluf(a1); o.z = siluf(a2); o.w = siluf(a3);
  *(float4*)(xpc + (size_t)row * DINNER + d) = o;
}

// ---------------- chunked selective scan ----------------
// thread t -> n = t&15 (state), c = (t>>4)&15 (chunk), g = t>>8 = b*DINNER+d.
// One 256-thread block covers all 16 chunks x 16 states of one (b,d).

// pass1: per-chunk scan from zero state -> S; per-chunk sum of delta -> sdl
__global__ __launch_bounds__(256) void scan_pass1(
    const float* __restrict__ dlt, const float* __restrict__ u_,
    const float* __restrict__ xd, const float* __restrict__ Alog,
    float* __restrict__ Sws, float* __restrict__ sdlws)
{
  int t = blockIdx.x * 256 + threadIdx.x;    // NB*DINNER*NCH*16
  int n = t & 15;
  int c = (t >> 4) & (NCH - 1);
  int g = t >> 8;
  int d = g & (DINNER - 1);

  float An = -__expf(Alog[d * DSTATE + n]);
  int b = g >> 11;
  size_t r0 = (size_t)b * SEQ + (size_t)c * CLEN;

  float S = 0.f, sdl = 0.f;
  float dl = dlt[r0 * DINNER + d];
  float uu = u_ [r0 * DINNER + d];
  float Bn = xd [r0 * 96 + 64 + n];
  for (int l = 0; l < CLEN - 1; ++l) {
    size_t rr = r0 + l + 1;
    float dln = dlt[rr * DINNER + d];
    float uun = u_ [rr * DINNER + d];
    float Bnn = xd [rr * 96 + 64 + n];
    float a = __expf(dl * An);
    S = a * S + (dl * uu) * Bn;
    sdl += dl;
    dl = dln; uu = uun; Bn = Bnn;
  }
  float a = __expf(dl * An);
  S = a * S + (dl * uu) * Bn;
  sdl += dl;

  Sws[t] = S;
  if (n == 0) sdlws[g * NCH + c] = sdl;
}

// pass2: stitch chunk states sequentially (16 steps), emit entering state H per chunk
__global__ __launch_bounds__(256) void scan_pass2(
    const float* __restrict__ Sws, const float* __restrict__ sdlws,
    const float* __restrict__ Alog, float* __restrict__ Hws)
{
  int t = blockIdx.x * 256 + threadIdx.x;    // NB*DINNER*16
  int n = t & 15;
  int g = t >> 4;
  int d = g & (DINNER - 1);
  float An = -__expf(Alog[d * DSTATE + n]);

  float h = 0.f;
#pragma unroll
  for (int c = 0; c < NCH; ++c) {
    int idx = (g * NCH + c) * 16 + n;
    Hws[idx] = h;
    float P = __expf(An * sdlws[g * NCH + c]);
    h = P * h + Sws[idx];
  }
}

// pass3: re-run each chunk from its entering state, produce y (overwrites dlt)
__global__ __launch_bounds__(256) void scan_pass3(
    float* dy,                         // delta in, y out (aliased)
    const float* __restrict__ u_,      // xpc [BL, DINNER]
    const float* __restrict__ xd,      // xdbl [BL, 96]
    const float* __restrict__ xzb,     // xz [BL, 4096] (z half)
    const float* __restrict__ Alog,
    const float* __restrict__ Dv,
    const float* __restrict__ Hws)
{
  int t = blockIdx.x * 256 + threadIdx.x;    // NB*DINNER*NCH*16
  int n = t & 15;
  int c = (t >> 4) & (NCH - 1);
  int g = t >> 8;
  int d = g & (DINNER - 1);
  int b = g >> 11;

  float An = -__expf(Alog[d * DSTATE + n]);
  float Dd = Dv[d];
  size_t r0 = (size_t)b * SEQ + (size_t)c * CLEN;

  float h = Hws[t];

  float dl = dy [r0 * DINNER + d];
  float uu = u_ [r0 * DINNER + d];
  float Bn = xd [r0 * 96 + 64 + n];
  float Cn = xd [r0 * 96 + 80 + n];
  float zz = xzb[r0 * (2 * DINNER) + DINNER + d];

#define SCAN_STEP(RR)                                                     \
  {                                                                       \
    float a = __expf(dl * An);                                            \
    h = a * h + (dl * uu) * Bn;                                           \
    float yp = h * Cn;                                                    \
    yp += __shfl_xor(yp, 1);                                              \
    yp += __shfl_xor(yp, 2);                                              \
    yp += __shfl_xor(yp, 4);                                              \
    yp += __shfl_xor(yp, 8);                                              \
    if (n == 0) {                                                         \
      dy[(RR) * DINNER + d] = (yp + uu * Dd) * siluf(zz);                 \
    }                                                                     \
  }

  for (int l = 0; l < CLEN - 1; ++l) {
    size_t rr = r0 + l + 1;
    float dln = dy [rr * DINNER + d];
    float uun = u_ [rr * DINNER + d];
    float Bnn = xd [rr * 96 + 64 + n];
    float Cnn = xd [rr * 96 + 80 + n];
    float zzn = xzb[rr * (2 * DINNER) + DINNER + d];
    SCAN_STEP(r0 + l);
    dl = dln; uu = uun; Bn = Bnn; Cn = Cnn; zz = zzn;
  }
  SCAN_STEP(r0 + CLEN - 1);
#undef SCAN_STEP
}

// ---------------- RMSNorm (row = 1024) ----------------
template<int ADDRES>
__global__ __launch_bounds__(256) void rmsnorm_kernel(
    const float* __restrict__ x, const float* __restrict__ w,
    const float* __restrict__ res, float* __restrict__ out)
{
  int row = blockIdx.x, tid = threadIdx.x;
  float4 v = *(const float4*)(x + (size_t)row * DMODEL + tid * 4);
  float ss = v.x * v.x + v.y * v.y + v.z * v.z + v.w * v.w;
#pragma unroll
  for (int off = 32; off > 0; off >>= 1) ss += __shfl_xor(ss, off);
  __shared__ float sb[4];
  if ((tid & 63) == 0) sb[tid >> 6] = ss;
  __syncthreads();
  ss = (sb[0] + sb[1]) + (sb[2] + sb[3]);
  float sc = rsqrtf(ss * (1.f / DMODEL) + 1e-5f);
  float4 wv = *(const float4*)(w + tid * 4);
  float4 o;
  o.x = v.x * sc * wv.x; o.y = v.y * sc * wv.y;
  o.z = v.z * sc * wv.z; o.w = v.w * sc * wv.w;
  if (ADDRES) {
    float4 rv = *(const float4*)(res + (size_t)row * DMODEL + tid * 4);
    o.x += rv.x; o.y += rv.y; o.z += rv.z; o.w += rv.w;
  }
  *(float4*)(out + (size_t)row * DMODEL + tid * 4) = o;
}

// ---------------- launcher ----------------
extern "C" void kernel_launch(void* const* d_in, const int* in_sizes, int n_in,
                              void* d_out, int out_size, void* d_ws, size_t ws_size,
                              hipStream_t stream) {
  const float* x        = (const float*)d_in[0];
  const float* emb_w    = (const float*)d_in[1];
  const float* emb_b    = (const float*)d_in[2];
  const float* in_projw = (const float*)d_in[3];
  const float* conv_w   = (const float*)d_in[4];
  const float* conv_b   = (const float*)d_in[5];
  const float* x_projw  = (const float*)d_in[6];
  const float* dt_projw = (const float*)d_in[7];
  const float* dt_projb = (const float*)d_in[8];
  const float* A_log    = (const float*)d_in[9];
  const float* Dvec     = (const float*)d_in[10];
  const float* out_projw= (const float*)d_in[11];
  const float* norm_w   = (const float*)d_in[12];
  const float* head_w   = (const float*)d_in[13];

  float* ws = (float*)d_ws;
  float* h    = ws;                                  //  4M floats [BL,1024]
  float* xz   = h    + (size_t)BL * DMODEL;          // 16M floats [BL,4096]
  float* xpc  = xz   + (size_t)BL * 2 * DINNER;      //  8M floats [BL,2048]
  float* dlt  = xpc  + (size_t)BL * DINNER;          //  8M floats [BL,2048] (delta -> y)
  float* xdbl = dlt  + (size_t)BL * DINNER;          //  [BL,96]
  float* Sws  = xdbl + (size_t)BL * 96;              //  1.05M floats
  float* Hws  = Sws  + (size_t)NB * DINNER * DSTATE * NCH;
  float* sdlw = Hws  + (size_t)NB * DINNER * DSTATE * NCH;  // 65536 floats
  float* tmp  = xz;                                  // alias: out_proj result [BL,1024]
  float* hn   = xz + (size_t)BL * DMODEL;            // alias: final norm [BL,1024]

  dim3 blk(256);

  // h = x @ emb_w^T + emb_b
  gemm_bt<0><<<dim3(BL / 128, DMODEL / 128), blk, 0, stream>>>(
      x, DMODEL, emb_w, DMODEL, h, DMODEL, DMODEL, DMODEL, emb_b);

  for (int i = 0; i < NLAYER; ++i) {
    const float* in_w = in_projw + (size_t)i * 2 * DINNER * DMODEL;
    const float* cw   = conv_w   + (size_t)i * DINNER * 4;
    const float* cb   = conv_b   + (size_t)i * DINNER;
    const float* xpw  = x_projw  + (size_t)i * (DTRANK + 2 * DSTATE) * DINNER;
    const float* dtw  = dt_projw + (size_t)i * DINNER * DTRANK;
    const float* dtb  = dt_projb + (size_t)i * DINNER;
    const float* Al   = A_log    + (size_t)i * DINNER * DSTATE;
    const float* Dl   = Dvec     + (size_t)i * DINNER;
    const float* ow   = out_projw+ (size_t)i * DMODEL * DINNER;

    // xz = h @ in_w^T   [BL, 4096]
    gemm_bt<0><<<dim3(BL / 128, (2 * DINNER) / 128), blk, 0, stream>>>(
        h, DMODEL, in_w, DMODEL, xz, 2 * DINNER, 2 * DINNER, DMODEL, nullptr);
    // xpc = silu(causal_conv(xz[:, :2048]))
    conv_silu_kernel<<<dim3(BL * (DINNER / 4) / 256), blk, 0, stream>>>(xz, cw, cb, xpc);
    // xdbl = xpc @ xpw^T  [BL, 96]
    gemm_bt<0><<<dim3(BL / 128, 1), blk, 0, stream>>>(
        xpc, DINNER, xpw, DINNER, xdbl, 96, 96, DINNER, nullptr);
    // delta = softplus(xdbl[:, :64] @ dtw^T + dtb)  [BL, 2048]
    gemm_bt<1><<<dim3(BL / 128, DINNER / 128), blk, 0, stream>>>(
        xdbl, 96, dtw, DTRANK, dlt, DINNER, DINNER, DTRANK, dtb);
    // chunked selective scan
    scan_pass1<<<dim3(NB * DINNER * DSTATE * NCH / 256), blk, 0, stream>>>(
        dlt, xpc, xdbl, Al, Sws, sdlw);
    scan_pass2<<<dim3(NB * DINNER * DSTATE / 256), blk, 0, stream>>>(
        Sws, sdlw, Al, Hws);
    scan_pass3<<<dim3(NB * DINNER * DSTATE * NCH / 256), blk, 0, stream>>>(
        dlt, xpc, xdbl, xz, Al, Dl, Hws);
    // tmp = y @ ow^T  [BL, 1024]
    gemm_bt<0><<<dim3(BL / 128, DMODEL / 128), blk, 0, stream>>>(
        dlt, DINNER, ow, DINNER, tmp, DMODEL, DMODEL, DINNER, nullptr);
    // h = h + rmsnorm(tmp) * norm_w
    rmsnorm_kernel<1><<<dim3(BL), blk, 0, stream>>>(tmp, norm_w, h, h);
  }

  // final norm + head
  rmsnorm_kernel<0><<<dim3(BL), blk, 0, stream>>>(h, norm_w, nullptr, hn);
  gemm_bt<0><<<dim3(BL / 128, DMODEL / 128), blk, 0, stream>>>(
      hn, DMODEL, head_w, DMODEL, (float*)d_out, DMODEL, DMODEL, DMODEL, nullptr);
}

// Round 3
// 2368.183 us; speedup vs baseline: 2.0004x; 1.5156x over previous
//
#include <hip/hip_runtime.h>
#include <hip/hip_bf16.h>

// ---------------- constants (fixed problem shape) ----------------
#define DMODEL 1024
#define DINNER 2048
#define DSTATE 16
#define DTRANK 64
#define NLAYER 4
#define SEQ    2048
#define NB     2
#define BL     (NB*SEQ)   // 4096 token rows

// chunked scan
#define NCH   32
#define CLEN  (SEQ / NCH)   // 64

typedef __bf16 bf16x8 __attribute__((ext_vector_type(8)));
typedef float  f32x4  __attribute__((ext_vector_type(4)));
typedef unsigned short u16x8 __attribute__((ext_vector_type(8)));

__device__ __forceinline__ unsigned short f2bf(float f) {
  unsigned int x = __builtin_bit_cast(unsigned int, f);
  x += 0x7fffu + ((x >> 16) & 1u);   // round-to-nearest-even
  return (unsigned short)(x >> 16);
}
__device__ __forceinline__ float softplusf(float x) {
  return (x > 20.f) ? x : log1pf(__expf(x));
}
__device__ __forceinline__ float siluf(float x) {
  return x * (1.f / (1.f + __expf(-x)));
}

__device__ __forceinline__ void pack16(const float* p, u16x8& u0, u16x8& u1) {
  float4 f0 = *(const float4*)(p);
  float4 f1 = *(const float4*)(p + 4);
  float4 f2 = *(const float4*)(p + 8);
  float4 f3 = *(const float4*)(p + 12);
  u0[0]=f2bf(f0.x); u0[1]=f2bf(f0.y); u0[2]=f2bf(f0.z); u0[3]=f2bf(f0.w);
  u0[4]=f2bf(f1.x); u0[5]=f2bf(f1.y); u0[6]=f2bf(f1.z); u0[7]=f2bf(f1.w);
  u1[0]=f2bf(f2.x); u1[1]=f2bf(f2.y); u1[2]=f2bf(f2.z); u1[3]=f2bf(f2.w);
  u1[4]=f2bf(f3.x); u1[5]=f2bf(f3.y); u1[6]=f2bf(f3.z); u1[7]=f2bf(f3.w);
}

// ---------------- generic GEMM: C[M,N] = act(A[M,K] * B[N,K]^T + bias) ----------------
template<int ACT>
__global__ __launch_bounds__(256) void gemm_bt(
    const float* __restrict__ A, int lda,
    const float* __restrict__ B, int ldb,
    float* __restrict__ C, int ldc,
    int N, int K, const float* __restrict__ bias)
{
  __shared__ alignas(16) unsigned short As[128 * 32];
  __shared__ alignas(16) unsigned short Bs[128 * 32];

  const int tid  = threadIdx.x;
  const int bm   = blockIdx.x, bn = blockIdx.y;
  const int wave = tid >> 6,  lane = tid & 63;
  const int wm   = wave >> 1, wn   = wave & 1;
  const int fr   = lane & 15, fq   = lane >> 4;

  const int r  = tid >> 1, hh = tid & 1;
  const int sw = (r & 7) << 4;
  const int offS0 = ((r * 64 + hh * 32)     ) ^ sw;
  const int offS1 = ((r * 64 + hh * 32 + 16)) ^ sw;

  const int rowA = bm * 128 + r;
  const int rowB = bn * 128 + r;
  const float* aRow = A + (size_t)rowA * lda + hh * 16;
  const float* bRow = B + (size_t)rowB * ldb + hh * 16;
  const bool bValid = (rowB < N);

  f32x4 acc[4][4] = {};

  for (int k0 = 0; k0 < K; k0 += 32) {
    {
      u16x8 u0, u1;
      pack16(aRow + k0, u0, u1);
      *(u16x8*)((char*)As + offS0) = u0;
      *(u16x8*)((char*)As + offS1) = u1;
    }
    {
      u16x8 u0 = {}, u1 = {};
      if (bValid) pack16(bRow + k0, u0, u1);
      *(u16x8*)((char*)Bs + offS0) = u0;
      *(u16x8*)((char*)Bs + offS1) = u1;
    }
    __syncthreads();

    bf16x8 af[4], bfr[4];
#pragma unroll
    for (int mi = 0; mi < 4; ++mi) {
      int ra = wm * 64 + mi * 16 + fr;
      af[mi] = *(const bf16x8*)((const char*)As + ((ra * 64 + fq * 16) ^ ((ra & 7) << 4)));
    }
#pragma unroll
    for (int nj = 0; nj < 4; ++nj) {
      int rb = wn * 64 + nj * 16 + fr;
      bfr[nj] = *(const bf16x8*)((const char*)Bs + ((rb * 64 + fq * 16) ^ ((rb & 7) << 4)));
    }
#pragma unroll
    for (int mi = 0; mi < 4; ++mi)
#pragma unroll
      for (int nj = 0; nj < 4; ++nj)
        acc[mi][nj] = __builtin_amdgcn_mfma_f32_16x16x32_bf16(af[mi], bfr[nj], acc[mi][nj], 0, 0, 0);
    __syncthreads();
  }

#pragma unroll
  for (int mi = 0; mi < 4; ++mi)
#pragma unroll
    for (int nj = 0; nj < 4; ++nj)
#pragma unroll
      for (int q = 0; q < 4; ++q) {
        int row = bm * 128 + wm * 64 + mi * 16 + fq * 4 + q;
        int col = bn * 128 + wn * 64 + nj * 16 + fr;
        if (col < N) {
          float v = acc[mi][nj][q];
          if (bias) v += bias[col];
          if (ACT == 1) v = softplusf(v);
          C[(size_t)row * ldc + col] = v;
        }
      }
}

// ---------------- depthwise causal conv (K=4) + SiLU ----------------
__global__ __launch_bounds__(256) void conv_silu_kernel(
    const float* __restrict__ xz, const float* __restrict__ cw,
    const float* __restrict__ cb, float* __restrict__ xpc)
{
  int idx = blockIdx.x * 256 + threadIdx.x;   // BL * 512
  int dq  = idx & 511;
  int row = idx >> 9;
  int l   = row & (SEQ - 1);
  int d   = dq << 2;

  float4 bv = *(const float4*)(cb + d);
  float4 w0 = *(const float4*)(cw + (size_t)(d + 0) * 4);
  float4 w1 = *(const float4*)(cw + (size_t)(d + 1) * 4);
  float4 w2 = *(const float4*)(cw + (size_t)(d + 2) * 4);
  float4 w3 = *(const float4*)(cw + (size_t)(d + 3) * 4);

  float a0 = bv.x, a1 = bv.y, a2 = bv.z, a3 = bv.w;
#pragma unroll
  for (int k = 0; k < 4; ++k) {
    int ls = l - 3 + k;
    if (ls >= 0) {
      float4 xv = *(const float4*)(xz + (size_t)(row - 3 + k) * (2 * DINNER) + d);
      float c0 = (k == 0) ? w0.x : (k == 1) ? w0.y : (k == 2) ? w0.z : w0.w;
      float c1 = (k == 0) ? w1.x : (k == 1) ? w1.y : (k == 2) ? w1.z : w1.w;
      float c2 = (k == 0) ? w2.x : (k == 1) ? w2.y : (k == 2) ? w2.z : w2.w;
      float c3 = (k == 0) ? w3.x : (k == 1) ? w3.y : (k == 2) ? w3.z : w3.w;
      a0 += xv.x * c0; a1 += xv.y * c1; a2 += xv.z * c2; a3 += xv.w * c3;
    }
  }
  float4 o;
  o.x = siluf(a0); o.y = siluf(a1); o.z = siluf(a2); o.w = siluf(a3);
  *(float4*)(xpc + (size_t)row * DINNER + d) = o;
}

// ---------------- chunked selective scan, d-major, 16 states in registers ------
// thread t: d = t & 2047 (fast axis -> coalesced), (b,c) = t >> 11.
// S/H layout: [(b*NCH+c)][n][d] -> base + n*DINNER, coalesced across d.

__global__ __launch_bounds__(64) void scan_pass1(
    const float* __restrict__ dlt, const float* __restrict__ u_,
    const float* __restrict__ xd, const float* __restrict__ Alog,
    float* __restrict__ Sws, float* __restrict__ sdlws)
{
  int t = blockIdx.x * 64 + threadIdx.x;     // NB*NCH*DINNER
  int d = t & (DINNER - 1);
  int cb = t >> 11;
  int c = cb & (NCH - 1);
  int b = cb >> 5;
  size_t r0 = (size_t)b * SEQ + (size_t)c * CLEN;

  float An[16];
  {
    const float4* Ap = (const float4*)(Alog + (size_t)d * 16);
#pragma unroll
    for (int q = 0; q < 4; ++q) {
      float4 a = Ap[q];
      An[4*q+0] = -__expf(a.x); An[4*q+1] = -__expf(a.y);
      An[4*q+2] = -__expf(a.z); An[4*q+3] = -__expf(a.w);
    }
  }

  float S[16];
#pragma unroll
  for (int n = 0; n < 16; ++n) S[n] = 0.f;
  float sdl = 0.f;

#pragma unroll 2
  for (int l = 0; l < CLEN; ++l) {
    size_t rr = r0 + l;
    float dl = dlt[rr * DINNER + d];
    float uu = u_ [rr * DINNER + d];
    const float4* Bp = (const float4*)(xd + rr * 96 + 64);
    float4 B0 = Bp[0], B1 = Bp[1], B2 = Bp[2], B3 = Bp[3];
    float du = dl * uu;
    sdl += dl;
    float Bv[16] = {B0.x,B0.y,B0.z,B0.w, B1.x,B1.y,B1.z,B1.w,
                    B2.x,B2.y,B2.z,B2.w, B3.x,B3.y,B3.z,B3.w};
#pragma unroll
    for (int n = 0; n < 16; ++n)
      S[n] = __expf(dl * An[n]) * S[n] + du * Bv[n];
  }

  size_t base = (size_t)cb * 16 * DINNER + d;
#pragma unroll
  for (int n = 0; n < 16; ++n) Sws[base + (size_t)n * DINNER] = S[n];
  sdlws[(size_t)cb * DINNER + d] = sdl;
}

// pass2: sequential stitch over chunks; overwrites S slots with entering state H.
// (SH aliases Sws — per (b,c,n,d) slot: read S, then write H; single-thread owned.)
__global__ __launch_bounds__(256) void scan_pass2(
    float* SH, const float* __restrict__ sdlws, const float* __restrict__ Alog)
{
  int t = blockIdx.x * 256 + threadIdx.x;    // NB*DINNER
  int d = t & (DINNER - 1);
  int b = t >> 11;

  float An[16];
  {
    const float4* Ap = (const float4*)(Alog + (size_t)d * 16);
#pragma unroll
    for (int q = 0; q < 4; ++q) {
      float4 a = Ap[q];
      An[4*q+0] = -__expf(a.x); An[4*q+1] = -__expf(a.y);
      An[4*q+2] = -__expf(a.z); An[4*q+3] = -__expf(a.w);
    }
  }

  float h[16];
#pragma unroll
  for (int n = 0; n < 16; ++n) h[n] = 0.f;

  for (int c = 0; c < NCH; ++c) {
    size_t bc = (size_t)(b * NCH + c);
    size_t base = bc * 16 * DINNER + d;
    float sdl = sdlws[bc * DINNER + d];
    float Sc[16];
#pragma unroll
    for (int n = 0; n < 16; ++n) Sc[n] = SH[base + (size_t)n * DINNER];
#pragma unroll
    for (int n = 0; n < 16; ++n) SH[base + (size_t)n * DINNER] = h[n];
#pragma unroll
    for (int n = 0; n < 16; ++n) h[n] = __expf(An[n] * sdl) * h[n] + Sc[n];
  }
}

// pass3: re-run each chunk from entering state, produce y (overwrites dlt)
__global__ __launch_bounds__(64) void scan_pass3(
    float* dy,                         // delta in, y out (aliased)
    const float* __restrict__ u_,      // xpc [BL, DINNER]
    const float* __restrict__ xd,      // xdbl [BL, 96]
    const float* __restrict__ xzb,     // xz [BL, 4096] (z half)
    const float* __restrict__ Alog,
    const float* __restrict__ Dv,
    const float* __restrict__ SH)      // entering states H
{
  int t = blockIdx.x * 64 + threadIdx.x;     // NB*NCH*DINNER
  int d = t & (DINNER - 1);
  int cb = t >> 11;
  int c = cb & (NCH - 1);
  int b = cb >> 5;
  size_t r0 = (size_t)b * SEQ + (size_t)c * CLEN;

  float An[16];
  {
    const float4* Ap = (const float4*)(Alog + (size_t)d * 16);
#pragma unroll
    for (int q = 0; q < 4; ++q) {
      float4 a = Ap[q];
      An[4*q+0] = -__expf(a.x); An[4*q+1] = -__expf(a.y);
      An[4*q+2] = -__expf(a.z); An[4*q+3] = -__expf(a.w);
    }
  }

  float h[16];
  {
    size_t base = (size_t)cb * 16 * DINNER + d;
#pragma unroll
    for (int n = 0; n < 16; ++n) h[n] = SH[base + (size_t)n * DINNER];
  }
  float Dd = Dv[d];

#pragma unroll 2
  for (int l = 0; l < CLEN; ++l) {
    size_t rr = r0 + l;
    float dl = dy [rr * DINNER + d];
    float uu = u_ [rr * DINNER + d];
    float zz = xzb[rr * (2 * DINNER) + DINNER + d];
    const float4* Bp = (const float4*)(xd + rr * 96 + 64);
    float4 B0 = Bp[0], B1 = Bp[1], B2 = Bp[2], B3 = Bp[3];
    const float4* Cp = (const float4*)(xd + rr * 96 + 80);
    float4 C0 = Cp[0], C1 = Cp[1], C2 = Cp[2], C3 = Cp[3];
    float Bv[16] = {B0.x,B0.y,B0.z,B0.w, B1.x,B1.y,B1.z,B1.w,
                    B2.x,B2.y,B2.z,B2.w, B3.x,B3.y,B3.z,B3.w};
    float Cv[16] = {C0.x,C0.y,C0.z,C0.w, C1.x,C1.y,C1.z,C1.w,
                    C2.x,C2.y,C2.z,C2.w, C3.x,C3.y,C3.z,C3.w};
    float du = dl * uu;
    float y = 0.f;
#pragma unroll
    for (int n = 0; n < 16; ++n) {
      h[n] = __expf(dl * An[n]) * h[n] + du * Bv[n];
      y += h[n] * Cv[n];
    }
    dy[rr * DINNER + d] = (y + uu * Dd) * siluf(zz);
  }
}

// ---------------- RMSNorm (row = 1024) ----------------
template<int ADDRES>
__global__ __launch_bounds__(256) void rmsnorm_kernel(
    const float* __restrict__ x, const float* __restrict__ w,
    const float* __restrict__ res, float* __restrict__ out)
{
  int row = blockIdx.x, tid = threadIdx.x;
  float4 v = *(const float4*)(x + (size_t)row * DMODEL + tid * 4);
  float ss = v.x * v.x + v.y * v.y + v.z * v.z + v.w * v.w;
#pragma unroll
  for (int off = 32; off > 0; off >>= 1) ss += __shfl_xor(ss, off);
  __shared__ float sb[4];
  if ((tid & 63) == 0) sb[tid >> 6] = ss;
  __syncthreads();
  ss = (sb[0] + sb[1]) + (sb[2] + sb[3]);
  float sc = rsqrtf(ss * (1.f / DMODEL) + 1e-5f);
  float4 wv = *(const float4*)(w + tid * 4);
  float4 o;
  o.x = v.x * sc * wv.x; o.y = v.y * sc * wv.y;
  o.z = v.z * sc * wv.z; o.w = v.w * sc * wv.w;
  if (ADDRES) {
    float4 rv = *(const float4*)(res + (size_t)row * DMODEL + tid * 4);
    o.x += rv.x; o.y += rv.y; o.z += rv.z; o.w += rv.w;
  }
  *(float4*)(out + (size_t)row * DMODEL + tid * 4) = o;
}

// ---------------- launcher ----------------
extern "C" void kernel_launch(void* const* d_in, const int* in_sizes, int n_in,
                              void* d_out, int out_size, void* d_ws, size_t ws_size,
                              hipStream_t stream) {
  const float* x        = (const float*)d_in[0];
  const float* emb_w    = (const float*)d_in[1];
  const float* emb_b    = (const float*)d_in[2];
  const float* in_projw = (const float*)d_in[3];
  const float* conv_w   = (const float*)d_in[4];
  const float* conv_b   = (const float*)d_in[5];
  const float* x_projw  = (const float*)d_in[6];
  const float* dt_projw = (const float*)d_in[7];
  const float* dt_projb = (const float*)d_in[8];
  const float* A_log    = (const float*)d_in[9];
  const float* Dvec     = (const float*)d_in[10];
  const float* out_projw= (const float*)d_in[11];
  const float* norm_w   = (const float*)d_in[12];
  const float* head_w   = (const float*)d_in[13];

  float* ws = (float*)d_ws;
  float* h    = ws;                                  //  4M floats [BL,1024]
  float* xz   = h    + (size_t)BL * DMODEL;          // 16M floats [BL,4096]
  float* xpc  = xz   + (size_t)BL * 2 * DINNER;      //  8M floats [BL,2048]
  float* dlt  = xpc  + (size_t)BL * DINNER;          //  8M floats [BL,2048] (delta -> y)
  float* xdbl = dlt  + (size_t)BL * DINNER;          //  [BL,96]
  float* Sws  = xdbl + (size_t)BL * 96;              //  NB*NCH*16*DINNER = 2.1M floats (S, then H)
  float* sdlw = Sws  + (size_t)NB * NCH * 16 * DINNER;  // NB*NCH*DINNER floats
  float* tmp  = xz;                                  // alias: out_proj result [BL,1024]
  float* hn   = xz + (size_t)BL * DMODEL;            // alias: final norm [BL,1024]

  dim3 blk(256);

  // h = x @ emb_w^T + emb_b
  gemm_bt<0><<<dim3(BL / 128, DMODEL / 128), blk, 0, stream>>>(
      x, DMODEL, emb_w, DMODEL, h, DMODEL, DMODEL, DMODEL, emb_b);

  for (int i = 0; i < NLAYER; ++i) {
    const float* in_w = in_projw + (size_t)i * 2 * DINNER * DMODEL;
    const float* cw   = conv_w   + (size_t)i * DINNER * 4;
    const float* cb   = conv_b   + (size_t)i * DINNER;
    const float* xpw  = x_projw  + (size_t)i * (DTRANK + 2 * DSTATE) * DINNER;
    const float* dtw  = dt_projw + (size_t)i * DINNER * DTRANK;
    const float* dtb  = dt_projb + (size_t)i * DINNER;
    const float* Al   = A_log    + (size_t)i * DINNER * DSTATE;
    const float* Dl   = Dvec     + (size_t)i * DINNER;
    const float* ow   = out_projw+ (size_t)i * DMODEL * DINNER;

    // xz = h @ in_w^T   [BL, 4096]
    gemm_bt<0><<<dim3(BL / 128, (2 * DINNER) / 128), blk, 0, stream>>>(
        h, DMODEL, in_w, DMODEL, xz, 2 * DINNER, 2 * DINNER, DMODEL, nullptr);
    // xpc = silu(causal_conv(xz[:, :2048]))
    conv_silu_kernel<<<dim3(BL * (DINNER / 4) / 256), blk, 0, stream>>>(xz, cw, cb, xpc);
    // xdbl = xpc @ xpw^T  [BL, 96]
    gemm_bt<0><<<dim3(BL / 128, 1), blk, 0, stream>>>(
        xpc, DINNER, xpw, DINNER, xdbl, 96, 96, DINNER, nullptr);
    // delta = softplus(xdbl[:, :64] @ dtw^T + dtb)  [BL, 2048]
    gemm_bt<1><<<dim3(BL / 128, DINNER / 128), blk, 0, stream>>>(
        xdbl, 96, dtw, DTRANK, dlt, DINNER, DINNER, DTRANK, dtb);
    // chunked selective scan (d-major)
    scan_pass1<<<dim3(NB * NCH * DINNER / 64), dim3(64), 0, stream>>>(
        dlt, xpc, xdbl, Al, Sws, sdlw);
    scan_pass2<<<dim3(NB * DINNER / 256), blk, 0, stream>>>(
        Sws, sdlw, Al);
    scan_pass3<<<dim3(NB * NCH * DINNER / 64), dim3(64), 0, stream>>>(
        dlt, xpc, xdbl, xz, Al, Dl, Sws);
    // tmp = y @ ow^T  [BL, 1024]
    gemm_bt<0><<<dim3(BL / 128, DMODEL / 128), blk, 0, stream>>>(
        dlt, DINNER, ow, DINNER, tmp, DMODEL, DMODEL, DINNER, nullptr);
    // h = h + rmsnorm(tmp) * norm_w
    rmsnorm_kernel<1><<<dim3(BL), blk, 0, stream>>>(tmp, norm_w, h, h);
  }

  // final norm + head
  rmsnorm_kernel<0><<<dim3(BL), blk, 0, stream>>>(h, norm_w, nullptr, hn);
  gemm_bt<0><<<dim3(BL / 128, DMODEL / 128), blk, 0, stream>>>(
      hn, DMODEL, head_w, DMODEL, (float*)d_out, DMODEL, DMODEL, DMODEL, nullptr);
}

// Round 4
// 1680.658 us; speedup vs baseline: 2.8188x; 1.4091x over previous
//
#include <hip/hip_runtime.h>
#include <hip/hip_bf16.h>

// ---------------- constants (fixed problem shape) ----------------
#define DMODEL 1024
#define DINNER 2048
#define DSTATE 16
#define DTRANK 64
#define NLAYER 4
#define SEQ    2048
#define NB     2
#define BL     (NB*SEQ)   // 4096 token rows

// chunked scan
#define NCH   32
#define CLEN  (SEQ / NCH)   // 64

// xdbl split-K
#define KSPLIT 8
#define NXD    96

typedef __bf16 bf16x8 __attribute__((ext_vector_type(8)));
typedef float  f32x4  __attribute__((ext_vector_type(4)));
typedef unsigned short u16x8 __attribute__((ext_vector_type(8)));

__device__ __forceinline__ unsigned short f2bf(float f) {
  unsigned int x = __builtin_bit_cast(unsigned int, f);
  x += 0x7fffu + ((x >> 16) & 1u);   // round-to-nearest-even
  return (unsigned short)(x >> 16);
}
__device__ __forceinline__ float softplusf(float x) {
  return (x > 20.f) ? x : log1pf(__expf(x));
}
__device__ __forceinline__ float siluf(float x) {
  return x * (1.f / (1.f + __expf(-x)));
}

__device__ __forceinline__ void gload_lds16(const void* g, void* l) {
  __builtin_amdgcn_global_load_lds(
      (const __attribute__((address_space(1))) void*)g,
      (__attribute__((address_space(3))) void*)l, 16, 0, 0);
}

__device__ __forceinline__ void pack16(const float* p, u16x8& u0, u16x8& u1) {
  float4 f0 = *(const float4*)(p);
  float4 f1 = *(const float4*)(p + 4);
  float4 f2 = *(const float4*)(p + 8);
  float4 f3 = *(const float4*)(p + 12);
  u0[0]=f2bf(f0.x); u0[1]=f2bf(f0.y); u0[2]=f2bf(f0.z); u0[3]=f2bf(f0.w);
  u0[4]=f2bf(f1.x); u0[5]=f2bf(f1.y); u0[6]=f2bf(f1.z); u0[7]=f2bf(f1.w);
  u1[0]=f2bf(f2.x); u1[1]=f2bf(f2.y); u1[2]=f2bf(f2.z); u1[3]=f2bf(f2.w);
  u1[4]=f2bf(f3.x); u1[5]=f2bf(f3.y); u1[6]=f2bf(f3.z); u1[7]=f2bf(f3.w);
}

// ---------------- f32 GEMM (legacy path, VALU-staged): C = act(A*B^T + bias) --
// Used for emb (writes f32 + bf16) and delta (softplus). N guarded, K mult of 32.
template<int ACT>
__global__ __launch_bounds__(256) void gemm_bt(
    const float* __restrict__ A, int lda,
    const float* __restrict__ B, int ldb,
    float* __restrict__ C, int ldc,
    unsigned short* __restrict__ Cbf,
    int N, int K, const float* __restrict__ bias)
{
  __shared__ alignas(16) unsigned short As[128 * 32];
  __shared__ alignas(16) unsigned short Bs[128 * 32];

  const int tid  = threadIdx.x;
  const int bm   = blockIdx.x, bn = blockIdx.y;
  const int wave = tid >> 6,  lane = tid & 63;
  const int wm   = wave >> 1, wn   = wave & 1;
  const int fr   = lane & 15, fq   = lane >> 4;

  const int r  = tid >> 1, hh = tid & 1;
  const int sw = (r & 7) << 4;
  const int offS0 = ((r * 64 + hh * 32)     ) ^ sw;
  const int offS1 = ((r * 64 + hh * 32 + 16)) ^ sw;

  const int rowA = bm * 128 + r;
  const int rowB = bn * 128 + r;
  const float* aRow = A + (size_t)rowA * lda + hh * 16;
  const float* bRow = B + (size_t)rowB * ldb + hh * 16;
  const bool bValid = (rowB < N);

  f32x4 acc[4][4] = {};

  for (int k0 = 0; k0 < K; k0 += 32) {
    {
      u16x8 u0, u1;
      pack16(aRow + k0, u0, u1);
      *(u16x8*)((char*)As + offS0) = u0;
      *(u16x8*)((char*)As + offS1) = u1;
    }
    {
      u16x8 u0 = {}, u1 = {};
      if (bValid) pack16(bRow + k0, u0, u1);
      *(u16x8*)((char*)Bs + offS0) = u0;
      *(u16x8*)((char*)Bs + offS1) = u1;
    }
    __syncthreads();

    bf16x8 af[4], bfr[4];
#pragma unroll
    for (int mi = 0; mi < 4; ++mi) {
      int ra = wm * 64 + mi * 16 + fr;
      af[mi] = *(const bf16x8*)((const char*)As + ((ra * 64 + fq * 16) ^ ((ra & 7) << 4)));
    }
#pragma unroll
    for (int nj = 0; nj < 4; ++nj) {
      int rb = wn * 64 + nj * 16 + fr;
      bfr[nj] = *(const bf16x8*)((const char*)Bs + ((rb * 64 + fq * 16) ^ ((rb & 7) << 4)));
    }
#pragma unroll
    for (int mi = 0; mi < 4; ++mi)
#pragma unroll
      for (int nj = 0; nj < 4; ++nj)
        acc[mi][nj] = __builtin_amdgcn_mfma_f32_16x16x32_bf16(af[mi], bfr[nj], acc[mi][nj], 0, 0, 0);
    __syncthreads();
  }

#pragma unroll
  for (int mi = 0; mi < 4; ++mi)
#pragma unroll
    for (int nj = 0; nj < 4; ++nj)
#pragma unroll
      for (int q = 0; q < 4; ++q) {
        int row = bm * 128 + wm * 64 + mi * 16 + fq * 4 + q;
        int col = bn * 128 + wn * 64 + nj * 16 + fr;
        if (col < N) {
          float v = acc[mi][nj][q];
          if (bias) v += bias[col];
          if (ACT == 1) v = softplusf(v);
          C[(size_t)row * ldc + col] = v;
          if (Cbf) Cbf[(size_t)row * ldc + col] = f2bf(v);
        }
      }
}

// ---------------- bf16 GEMM (m97 structure): C = A*B^T ----------------
// A [M,K] bf16, B [N,K] bf16, M,N multiples of 128, K multiple of 32.
// global_load_lds width-16, linear LDS, 2-barrier K loop.
__global__ __launch_bounds__(256) void gemm_bf(
    const unsigned short* __restrict__ A, int lda,
    const unsigned short* __restrict__ B, int ldb,
    float* __restrict__ C, int ldc, int K)
{
  __shared__ alignas(16) unsigned short As[128 * 32];
  __shared__ alignas(16) unsigned short Bs[128 * 32];

  const int tid  = threadIdx.x;
  const int bm   = blockIdx.x, bn = blockIdx.y;
  const int wave = tid >> 6,  lane = tid & 63;
  const int wm   = wave >> 1, wn   = wave & 1;
  const int fr   = lane & 15, fq   = lane >> 4;
  const int lrow = lane >> 2, lcol = (lane & 3) * 8;   // staging row/elem-col within 16-row chunk

  const unsigned short* Abase = A + (size_t)(bm * 128) * lda;
  const unsigned short* Bbase = B + (size_t)(bn * 128) * ldb;

  f32x4 acc[4][4] = {};

  for (int k0 = 0; k0 < K; k0 += 32) {
#pragma unroll
    for (int j = 0; j < 2; ++j) {
      int row = wave * 32 + j * 16 + lrow;
      // LDS dest: wave-uniform chunk base; HW adds lane*16 bytes.
      gload_lds16(Abase + (size_t)row * lda + k0 + lcol,
                  (char*)As + wave * 2048 + j * 1024);
      gload_lds16(Bbase + (size_t)row * ldb + k0 + lcol,
                  (char*)Bs + wave * 2048 + j * 1024);
    }
    __syncthreads();

    bf16x8 af[4], bfr[4];
#pragma unroll
    for (int mi = 0; mi < 4; ++mi) {
      int ra = wm * 64 + mi * 16 + fr;
      af[mi] = *(const bf16x8*)((const char*)As + ra * 64 + fq * 16);
    }
#pragma unroll
    for (int nj = 0; nj < 4; ++nj) {
      int rb = wn * 64 + nj * 16 + fr;
      bfr[nj] = *(const bf16x8*)((const char*)Bs + rb * 64 + fq * 16);
    }
#pragma unroll
    for (int mi = 0; mi < 4; ++mi)
#pragma unroll
      for (int nj = 0; nj < 4; ++nj)
        acc[mi][nj] = __builtin_amdgcn_mfma_f32_16x16x32_bf16(af[mi], bfr[nj], acc[mi][nj], 0, 0, 0);
    __syncthreads();
  }

#pragma unroll
  for (int mi = 0; mi < 4; ++mi)
#pragma unroll
    for (int nj = 0; nj < 4; ++nj)
#pragma unroll
      for (int q = 0; q < 4; ++q) {
        int row = bm * 128 + wm * 64 + mi * 16 + fq * 4 + q;
        int col = bn * 128 + wn * 64 + nj * 16 + fr;
        C[(size_t)row * ldc + col] = acc[mi][nj][q];
      }
}

// ---------------- split-K thin GEMM for xdbl: part[z] = xpc * xpw^T (K-slice) --
// A [4096,2048] f32, B [96,2048] f32, grid (32,1,KSPLIT), slice K=256.
__global__ __launch_bounds__(256) void gemm_xdbl(
    const float* __restrict__ A, const float* __restrict__ B,
    float* __restrict__ part)
{
  __shared__ alignas(16) unsigned short As[128 * 32];
  __shared__ alignas(16) unsigned short Bs[128 * 32];

  const int tid  = threadIdx.x;
  const int bm   = blockIdx.x;
  const int z    = blockIdx.z;
  const int wave = tid >> 6,  lane = tid & 63;
  const int wm   = wave >> 1, wn   = wave & 1;
  const int fr   = lane & 15, fq   = lane >> 4;

  const int r  = tid >> 1, hh = tid & 1;
  const int sw = (r & 7) << 4;
  const int offS0 = ((r * 64 + hh * 32)     ) ^ sw;
  const int offS1 = ((r * 64 + hh * 32 + 16)) ^ sw;

  const float* aRow = A + (size_t)(bm * 128 + r) * DINNER + hh * 16;
  const float* bRow = B + (size_t)r * DINNER + hh * 16;
  const bool bValid = (r < NXD);

  f32x4 acc[4][4] = {};

  const int kbeg = z * (DINNER / KSPLIT);
  for (int k0 = kbeg; k0 < kbeg + DINNER / KSPLIT; k0 += 32) {
    {
      u16x8 u0, u1;
      pack16(aRow + k0, u0, u1);
      *(u16x8*)((char*)As + offS0) = u0;
      *(u16x8*)((char*)As + offS1) = u1;
    }
    {
      u16x8 u0 = {}, u1 = {};
      if (bValid) pack16(bRow + k0, u0, u1);
      *(u16x8*)((char*)Bs + offS0) = u0;
      *(u16x8*)((char*)Bs + offS1) = u1;
    }
    __syncthreads();

    bf16x8 af[4], bfr[4];
#pragma unroll
    for (int mi = 0; mi < 4; ++mi) {
      int ra = wm * 64 + mi * 16 + fr;
      af[mi] = *(const bf16x8*)((const char*)As + ((ra * 64 + fq * 16) ^ ((ra & 7) << 4)));
    }
#pragma unroll
    for (int nj = 0; nj < 4; ++nj) {
      int rb = wn * 64 + nj * 16 + fr;
      bfr[nj] = *(const bf16x8*)((const char*)Bs + ((rb * 64 + fq * 16) ^ ((rb & 7) << 4)));
    }
#pragma unroll
    for (int mi = 0; mi < 4; ++mi)
#pragma unroll
      for (int nj = 0; nj < 4; ++nj)
        acc[mi][nj] = __builtin_amdgcn_mfma_f32_16x16x32_bf16(af[mi], bfr[nj], acc[mi][nj], 0, 0, 0);
    __syncthreads();
  }

#pragma unroll
  for (int mi = 0; mi < 4; ++mi)
#pragma unroll
    for (int nj = 0; nj < 4; ++nj)
#pragma unroll
      for (int q = 0; q < 4; ++q) {
        int row = bm * 128 + wm * 64 + mi * 16 + fq * 4 + q;
        int col = wn * 64 + nj * 16 + fr;
        if (col < NXD)
          part[((size_t)z * BL + row) * NXD + col] = acc[mi][nj][q];
      }
}

__global__ __launch_bounds__(256) void reduce_xdbl(
    const float* __restrict__ part, float* __restrict__ xdbl)
{
  int i = blockIdx.x * 256 + threadIdx.x;   // BL*NXD
  float s = 0.f;
#pragma unroll
  for (int z = 0; z < KSPLIT; ++z) s += part[(size_t)z * BL * NXD + i];
  xdbl[i] = s;
}

// ---------------- f32 -> bf16 convert (n multiple of 1024) ----------------
__global__ __launch_bounds__(256) void cvt_bf16(
    const float* __restrict__ in, unsigned short* __restrict__ out)
{
  int i = (blockIdx.x * 256 + threadIdx.x) * 4;
  float4 v = *(const float4*)(in + i);
  ushort4 o;
  o.x = f2bf(v.x); o.y = f2bf(v.y); o.z = f2bf(v.z); o.w = f2bf(v.w);
  *(ushort4*)(out + i) = o;
}

// ---------------- depthwise causal conv (K=4) + SiLU ----------------
__global__ __launch_bounds__(256) void conv_silu_kernel(
    const float* __restrict__ xz, const float* __restrict__ cw,
    const float* __restrict__ cb, float* __restrict__ xpc)
{
  int idx = blockIdx.x * 256 + threadIdx.x;   // BL * 512
  int dq  = idx & 511;
  int row = idx >> 9;
  int l   = row & (SEQ - 1);
  int d   = dq << 2;

  float4 bv = *(const float4*)(cb + d);
  float4 w0 = *(const float4*)(cw + (size_t)(d + 0) * 4);
  float4 w1 = *(const float4*)(cw + (size_t)(d + 1) * 4);
  float4 w2 = *(const float4*)(cw + (size_t)(d + 2) * 4);
  float4 w3 = *(const float4*)(cw + (size_t)(d + 3) * 4);

  float a0 = bv.x, a1 = bv.y, a2 = bv.z, a3 = bv.w;
#pragma unroll
  for (int k = 0; k < 4; ++k) {
    int ls = l - 3 + k;
    if (ls >= 0) {
      float4 xv = *(const float4*)(xz + (size_t)(row - 3 + k) * (2 * DINNER) + d);
      float c0 = (k == 0) ? w0.x : (k == 1) ? w0.y : (k == 2) ? w0.z : w0.w;
      float c1 = (k == 0) ? w1.x : (k == 1) ? w1.y : (k == 2) ? w1.z : w1.w;
      float c2 = (k == 0) ? w2.x : (k == 1) ? w2.y : (k == 2) ? w2.z : w2.w;
      float c3 = (k == 0) ? w3.x : (k == 1) ? w3.y : (k == 2) ? w3.z : w3.w;
      a0 += xv.x * c0; a1 += xv.y * c1; a2 += xv.z * c2; a3 += xv.w * c3;
    }
  }
  float4 o;
  o.x = siluf(a0); o.y = siluf(a1); o.z = siluf(a2); o.w = siluf(a3);
  *(float4*)(xpc + (size_t)row * DINNER + d) = o;
}

// ---------------- chunked selective scan, d-major, 16 states in registers ------
__global__ __launch_bounds__(64) void scan_pass1(
    const float* __restrict__ dlt, const float* __restrict__ u_,
    const float* __restrict__ xd, const float* __restrict__ Alog,
    float* __restrict__ Sws, float* __restrict__ sdlws)
{
  int t = blockIdx.x * 64 + threadIdx.x;     // NB*NCH*DINNER
  int d = t & (DINNER - 1);
  int cb = t >> 11;
  int c = cb & (NCH - 1);
  int b = cb >> 5;
  size_t r0 = (size_t)b * SEQ + (size_t)c * CLEN;

  float An[16];
  {
    const float4* Ap = (const float4*)(Alog + (size_t)d * 16);
#pragma unroll
    for (int q = 0; q < 4; ++q) {
      float4 a = Ap[q];
      An[4*q+0] = -__expf(a.x); An[4*q+1] = -__expf(a.y);
      An[4*q+2] = -__expf(a.z); An[4*q+3] = -__expf(a.w);
    }
  }

  float S[16];
#pragma unroll
  for (int n = 0; n < 16; ++n) S[n] = 0.f;
  float sdl = 0.f;

#pragma unroll 2
  for (int l = 0; l < CLEN; ++l) {
    size_t rr = r0 + l;
    float dl = dlt[rr * DINNER + d];
    float uu = u_ [rr * DINNER + d];
    const float4* Bp = (const float4*)(xd + rr * 96 + 64);
    float4 B0 = Bp[0], B1 = Bp[1], B2 = Bp[2], B3 = Bp[3];
    float du = dl * uu;
    sdl += dl;
    float Bv[16] = {B0.x,B0.y,B0.z,B0.w, B1.x,B1.y,B1.z,B1.w,
                    B2.x,B2.y,B2.z,B2.w, B3.x,B3.y,B3.z,B3.w};
#pragma unroll
    for (int n = 0; n < 16; ++n)
      S[n] = __expf(dl * An[n]) * S[n] + du * Bv[n];
  }

  size_t base = (size_t)cb * 16 * DINNER + d;
#pragma unroll
  for (int n = 0; n < 16; ++n) Sws[base + (size_t)n * DINNER] = S[n];
  sdlws[(size_t)cb * DINNER + d] = sdl;
}

__global__ __launch_bounds__(256) void scan_pass2(
    float* SH, const float* __restrict__ sdlws, const float* __restrict__ Alog)
{
  int t = blockIdx.x * 256 + threadIdx.x;    // NB*DINNER
  int d = t & (DINNER - 1);
  int b = t >> 11;

  float An[16];
  {
    const float4* Ap = (const float4*)(Alog + (size_t)d * 16);
#pragma unroll
    for (int q = 0; q < 4; ++q) {
      float4 a = Ap[q];
      An[4*q+0] = -__expf(a.x); An[4*q+1] = -__expf(a.y);
      An[4*q+2] = -__expf(a.z); An[4*q+3] = -__expf(a.w);
    }
  }

  float h[16];
#pragma unroll
  for (int n = 0; n < 16; ++n) h[n] = 0.f;

  for (int c = 0; c < NCH; ++c) {
    size_t bc = (size_t)(b * NCH + c);
    size_t base = bc * 16 * DINNER + d;
    float sdl = sdlws[bc * DINNER + d];
    float Sc[16];
#pragma unroll
    for (int n = 0; n < 16; ++n) Sc[n] = SH[base + (size_t)n * DINNER];
#pragma unroll
    for (int n = 0; n < 16; ++n) SH[base + (size_t)n * DINNER] = h[n];
#pragma unroll
    for (int n = 0; n < 16; ++n) h[n] = __expf(An[n] * sdl) * h[n] + Sc[n];
  }
}

// pass3: re-run each chunk from entering state, write y as bf16 (feeds out_proj)
__global__ __launch_bounds__(64) void scan_pass3(
    const float* __restrict__ dlt,     // delta
    const float* __restrict__ u_,      // xpc [BL, DINNER]
    const float* __restrict__ xd,      // xdbl [BL, 96]
    const float* __restrict__ xzb,     // xz [BL, 4096] (z half)
    const float* __restrict__ Alog,
    const float* __restrict__ Dv,
    const float* __restrict__ SH,      // entering states H
    unsigned short* __restrict__ ybf)  // y out, bf16 [BL, DINNER]
{
  int t = blockIdx.x * 64 + threadIdx.x;     // NB*NCH*DINNER
  int d = t & (DINNER - 1);
  int cb = t >> 11;
  int c = cb & (NCH - 1);
  int b = cb >> 5;
  size_t r0 = (size_t)b * SEQ + (size_t)c * CLEN;

  float An[16];
  {
    const float4* Ap = (const float4*)(Alog + (size_t)d * 16);
#pragma unroll
    for (int q = 0; q < 4; ++q) {
      float4 a = Ap[q];
      An[4*q+0] = -__expf(a.x); An[4*q+1] = -__expf(a.y);
      An[4*q+2] = -__expf(a.z); An[4*q+3] = -__expf(a.w);
    }
  }

  float h[16];
  {
    size_t base = (size_t)cb * 16 * DINNER + d;
#pragma unroll
    for (int n = 0; n < 16; ++n) h[n] = SH[base + (size_t)n * DINNER];
  }
  float Dd = Dv[d];

#pragma unroll 2
  for (int l = 0; l < CLEN; ++l) {
    size_t rr = r0 + l;
    float dl = dlt[rr * DINNER + d];
    float uu = u_ [rr * DINNER + d];
    float zz = xzb[rr * (2 * DINNER) + DINNER + d];
    const float4* Bp = (const float4*)(xd + rr * 96 + 64);
    float4 B0 = Bp[0], B1 = Bp[1], B2 = Bp[2], B3 = Bp[3];
    const float4* Cp = (const float4*)(xd + rr * 96 + 80);
    float4 C0 = Cp[0], C1 = Cp[1], C2 = Cp[2], C3 = Cp[3];
    float Bv[16] = {B0.x,B0.y,B0.z,B0.w, B1.x,B1.y,B1.z,B1.w,
                    B2.x,B2.y,B2.z,B2.w, B3.x,B3.y,B3.z,B3.w};
    float Cv[16] = {C0.x,C0.y,C0.z,C0.w, C1.x,C1.y,C1.z,C1.w,
                    C2.x,C2.y,C2.z,C2.w, C3.x,C3.y,C3.z,C3.w};
    float du = dl * uu;
    float y = 0.f;
#pragma unroll
    for (int n = 0; n < 16; ++n) {
      h[n] = __expf(dl * An[n]) * h[n] + du * Bv[n];
      y += h[n] * Cv[n];
    }
    ybf[rr * DINNER + d] = f2bf((y + uu * Dd) * siluf(zz));
  }
}

// ---------------- RMSNorm (row = 1024) ----------------
// ADDRES: add residual. WF32: write f32 out. WBF: write bf16 outbf.
template<int ADDRES, int WF32, int WBF>
__global__ __launch_bounds__(256) void rmsnorm_kernel(
    const float* __restrict__ x, const float* __restrict__ w,
    const float* __restrict__ res, float* __restrict__ out,
    unsigned short* __restrict__ outbf)
{
  int row = blockIdx.x, tid = threadIdx.x;
  float4 v = *(const float4*)(x + (size_t)row * DMODEL + tid * 4);
  float ss = v.x * v.x + v.y * v.y + v.z * v.z + v.w * v.w;
#pragma unroll
  for (int off = 32; off > 0; off >>= 1) ss += __shfl_xor(ss, off);
  __shared__ float sb[4];
  if ((tid & 63) == 0) sb[tid >> 6] = ss;
  __syncthreads();
  ss = (sb[0] + sb[1]) + (sb[2] + sb[3]);
  float sc = rsqrtf(ss * (1.f / DMODEL) + 1e-5f);
  float4 wv = *(const float4*)(w + tid * 4);
  float4 o;
  o.x = v.x * sc * wv.x; o.y = v.y * sc * wv.y;
  o.z = v.z * sc * wv.z; o.w = v.w * sc * wv.w;
  if (ADDRES) {
    float4 rv = *(const float4*)(res + (size_t)row * DMODEL + tid * 4);
    o.x += rv.x; o.y += rv.y; o.z += rv.z; o.w += rv.w;
  }
  if (WF32) *(float4*)(out + (size_t)row * DMODEL + tid * 4) = o;
  if (WBF) {
    ushort4 ob;
    ob.x = f2bf(o.x); ob.y = f2bf(o.y); ob.z = f2bf(o.z); ob.w = f2bf(o.w);
    *(ushort4*)(outbf + (size_t)row * DMODEL + tid * 4) = ob;
  }
}

// ---------------- launcher ----------------
extern "C" void kernel_launch(void* const* d_in, const int* in_sizes, int n_in,
                              void* d_out, int out_size, void* d_ws, size_t ws_size,
                              hipStream_t stream) {
  const float* x        = (const float*)d_in[0];
  const float* emb_w    = (const float*)d_in[1];
  const float* emb_b    = (const float*)d_in[2];
  const float* in_projw = (const float*)d_in[3];
  const float* conv_w   = (const float*)d_in[4];
  const float* conv_b   = (const float*)d_in[5];
  const float* x_projw  = (const float*)d_in[6];
  const float* dt_projw = (const float*)d_in[7];
  const float* dt_projb = (const float*)d_in[8];
  const float* A_log    = (const float*)d_in[9];
  const float* Dvec     = (const float*)d_in[10];
  const float* out_projw= (const float*)d_in[11];
  const float* norm_w   = (const float*)d_in[12];
  const float* head_w   = (const float*)d_in[13];

  float* ws = (float*)d_ws;
  float* h    = ws;                                    // 16 MB [BL,1024]
  float* xz   = h    + (size_t)BL * DMODEL;            // 64 MB [BL,4096]
  float* xpc  = xz   + (size_t)BL * 2 * DINNER;        // 32 MB [BL,2048]
  float* dlt  = xpc  + (size_t)BL * DINNER;            // 32 MB [BL,2048]
  float* xdbl = dlt  + (size_t)BL * DINNER;            // 1.5 MB [BL,96]
  float* SH   = xdbl + (size_t)BL * NXD;               // 8.4 MB
  float* sdlw = SH   + (size_t)NB * NCH * 16 * DINNER; // 0.5 MB
  float* part = sdlw + (size_t)NB * NCH * DINNER;      // 12.6 MB [8][BL][96]
  unsigned short* hbf = (unsigned short*)(part + (size_t)KSPLIT * BL * NXD); // 8 MB bf16 [BL,1024]
  unsigned short* ybf = hbf + (size_t)BL * DMODEL;     // 16 MB bf16 [BL,2048]
  unsigned short* wA  = ybf + (size_t)BL * DINNER;     // 8 MB bf16 (in_w / head_w)
  unsigned short* wB  = wA  + (size_t)2 * DINNER * DMODEL; // 4 MB bf16 (out_w)
  float* tmp  = xz;                                    // alias: out_proj result [BL,1024]

  dim3 blk(256);

  // h = x @ emb_w^T + emb_b  (f32 path; also emits bf16 h)
  gemm_bt<0><<<dim3(BL / 128, DMODEL / 128), blk, 0, stream>>>(
      x, DMODEL, emb_w, DMODEL, h, DMODEL, hbf, DMODEL, DMODEL, emb_b);

  for (int i = 0; i < NLAYER; ++i) {
    const float* in_w = in_projw + (size_t)i * 2 * DINNER * DMODEL;
    const float* cw   = conv_w   + (size_t)i * DINNER * 4;
    const float* cb   = conv_b   + (size_t)i * DINNER;
    const float* xpw  = x_projw  + (size_t)i * NXD * DINNER;
    const float* dtw  = dt_projw + (size_t)i * DINNER * DTRANK;
    const float* dtb  = dt_projb + (size_t)i * DINNER;
    const float* Al   = A_log    + (size_t)i * DINNER * DSTATE;
    const float* Dl   = Dvec     + (size_t)i * DINNER;
    const float* ow   = out_projw+ (size_t)i * DMODEL * DINNER;

    // convert in_proj weight to bf16
    cvt_bf16<<<dim3(2 * DINNER * DMODEL / 1024), blk, 0, stream>>>(in_w, wA);
    // xz = h @ in_w^T   [BL, 4096]  (bf16 fast path)
    gemm_bf<<<dim3(BL / 128, (2 * DINNER) / 128), blk, 0, stream>>>(
        hbf, DMODEL, wA, DMODEL, xz, 2 * DINNER, DMODEL);
    // xpc = silu(causal_conv(xz[:, :2048]))
    conv_silu_kernel<<<dim3(BL * (DINNER / 4) / 256), blk, 0, stream>>>(xz, cw, cb, xpc);
    // xdbl = xpc @ xpw^T  [BL, 96]  (split-K)
    gemm_xdbl<<<dim3(BL / 128, 1, KSPLIT), blk, 0, stream>>>(xpc, xpw, part);
    reduce_xdbl<<<dim3(BL * NXD / 256), blk, 0, stream>>>(part, xdbl);
    // delta = softplus(xdbl[:, :64] @ dtw^T + dtb)  [BL, 2048]
    gemm_bt<1><<<dim3(BL / 128, DINNER / 128), blk, 0, stream>>>(
        xdbl, NXD, dtw, DTRANK, dlt, DINNER, nullptr, DINNER, DTRANK, dtb);
    // chunked selective scan (d-major); pass3 emits bf16 y
    scan_pass1<<<dim3(NB * NCH * DINNER / 64), dim3(64), 0, stream>>>(
        dlt, xpc, xdbl, Al, SH, sdlw);
    scan_pass2<<<dim3(NB * DINNER / 256), blk, 0, stream>>>(SH, sdlw, Al);
    scan_pass3<<<dim3(NB * NCH * DINNER / 64), dim3(64), 0, stream>>>(
        dlt, xpc, xdbl, xz, Al, Dl, SH, ybf);
    // convert out_proj weight, then tmp = y @ ow^T  [BL, 1024]
    cvt_bf16<<<dim3(DMODEL * DINNER / 1024), blk, 0, stream>>>(ow, wB);
    gemm_bf<<<dim3(BL / 128, DMODEL / 128), blk, 0, stream>>>(
        ybf, DINNER, wB, DINNER, tmp, DMODEL, DINNER);
    // h = h + rmsnorm(tmp) * norm_w   (f32 + bf16)
    rmsnorm_kernel<1, 1, 1><<<dim3(BL), blk, 0, stream>>>(tmp, norm_w, h, h, hbf);
  }

  // final norm (bf16 only, into hbf) + head
  rmsnorm_kernel<0, 0, 1><<<dim3(BL), blk, 0, stream>>>(h, norm_w, nullptr, nullptr, hbf);
  cvt_bf16<<<dim3(DMODEL * DMODEL / 1024), blk, 0, stream>>>(head_w, wA);
  gemm_bf<<<dim3(BL / 128, DMODEL / 128), blk, 0, stream>>>(
      hbf, DMODEL, wA, DMODEL, (float*)d_out, DMODEL, DMODEL);
}